// Round 2
// baseline (541.847 us; speedup 1.0000x reference)
//
#include <hip/hip_runtime.h>
#include <hip/hip_bf16.h>

// SCM_39676907888322: sigmoid-gated cross attention.
// I/O is fp32 (per reference); internal compute bf16 MFMA.
// B=8, C=256, CI=128, H=W=48 -> N=2304.
// Kernel 0: convert 6 weight matrices fp32 -> bf16 into ws.
// Kernel A: QKV projections (6 GEMMs 128x2304x256 per batch) + concat passthrough.
//   Outputs: Qt/Kt transposed (n,128) bf16, V natural (128,n) bf16.
// Kernel B: fused flash-style sigmoid attention, P via per-wave LDS strip, fp32 out.

typedef __bf16 bf16;
typedef __bf16 bf16x8 __attribute__((ext_vector_type(8)));
typedef __bf16 bf16x4 __attribute__((ext_vector_type(4)));
typedef float f32x4 __attribute__((ext_vector_type(4)));

#define NB 8
#define NC 256
#define NCI 128
#define NHW 2304
#define NTILES 36   // 2304 / 64

__global__ __launch_bounds__(256) void wconv_kernel(
    const float* __restrict__ w0, const float* __restrict__ w1,
    const float* __restrict__ w2, const float* __restrict__ w3,
    const float* __restrict__ w4, const float* __restrict__ w5,
    bf16* __restrict__ dst)
{
    int idx = (blockIdx.x * 256 + threadIdx.x) * 8;   // 6*32768 total
    int m = idx >> 15;                                 // matrix id (block-uniform)
    int off = idx & 32767;
    const float* w = (m == 0) ? w0 : (m == 1) ? w1 : (m == 2) ? w2
                   : (m == 3) ? w3 : (m == 4) ? w4 : w5;
    f32x4 a0 = *(const f32x4*)(w + off);
    f32x4 a1 = *(const f32x4*)(w + off + 4);
    bf16x8 o;
    #pragma unroll
    for (int j = 0; j < 4; ++j) { o[j] = (bf16)a0[j]; o[4 + j] = (bf16)a1[j]; }
    *(bf16x8*)(dst + idx) = o;
}

__global__ __launch_bounds__(256) void qkv_kernel(
    const float* __restrict__ x1, const float* __restrict__ x2,
    const bf16* __restrict__ wb,
    const float* __restrict__ bv1, const float* __restrict__ bk1, const float* __restrict__ bq1,
    const float* __restrict__ bv2, const float* __restrict__ bk2, const float* __restrict__ bq2,
    bf16* __restrict__ Qt, bf16* __restrict__ Kt, bf16* __restrict__ Vt,
    float* __restrict__ out)
{
    // Xt[n][c] bf16, padded stride 264 (row start rotates 4 banks -> 2-way max = free)
    __shared__ __align__(16) bf16 Xt[64 * 264];

    int gid = blockIdx.x;
    int ntile = gid % NTILES;
    int s = (gid / NTILES) & 1;
    int b = gid / (2 * NTILES);
    int n0 = ntile * 64;

    const float* x = s ? x2 : x1;
    // wb layout: [v1,k1,q1,v2,k2,q2] each 128*256
    const bf16* wv = wb + (size_t)(s * 3 + 0) * (NCI * NC);
    const bf16* wk = wb + (size_t)(s * 3 + 1) * (NCI * NC);
    const bf16* wq = wb + (size_t)(s * 3 + 2) * (NCI * NC);
    const float* bv = s ? bv2 : bv1;
    const float* bk = s ? bk2 : bk1;
    const float* bq = s ? bq2 : bq1;
    float* outy = out + (size_t)s * (NB * 384 * NHW);

    int tid = threadIdx.x;
    // Stage X tile (256 c x 64 n) into LDS transposed (bf16); fuse fp32 concat passthrough.
    {
        int n_off = (tid & 7) * 8;       // 0,8,..,56
        int c0l = tid >> 3;              // 0..31
        #pragma unroll
        for (int i = 0; i < 8; ++i) {
            int c = c0l + i * 32;
            const float* src = x + ((size_t)(b * NC + c) * NHW + n0 + n_off);
            f32x4 a0 = *(const f32x4*)src;
            f32x4 a1 = *(const f32x4*)(src + 4);
            float* dsty = outy + ((size_t)(b * 384 + c) * NHW + n0 + n_off);
            *(f32x4*)dsty = a0;
            *(f32x4*)(dsty + 4) = a1;
            #pragma unroll
            for (int j = 0; j < 4; ++j) {
                Xt[(n_off + j) * 264 + c] = (bf16)a0[j];
                Xt[(n_off + 4 + j) * 264 + c] = (bf16)a1[j];
            }
        }
    }
    __syncthreads();

    int lane = tid & 63;
    int wid = tid >> 6;                  // wave 0..3 -> ci strip of 32
    int row = lane & 15, quad = lane >> 4;
    int ci_base = wid * 32;

    f32x4 acc[3][2][4];                  // [q,k,v][mi][ntile_j]
    #pragma unroll
    for (int t = 0; t < 3; ++t)
        #pragma unroll
        for (int mi = 0; mi < 2; ++mi)
            #pragma unroll
            for (int j = 0; j < 4; ++j)
                acc[t][mi][j] = (f32x4){0.f, 0.f, 0.f, 0.f};

    const bf16* wptr[3] = {wq, wk, wv};
    #pragma unroll
    for (int ks = 0; ks < 8; ++ks) {
        int c0 = ks * 32 + quad * 8;
        bf16x8 bfrag[4];
        #pragma unroll
        for (int j = 0; j < 4; ++j)
            bfrag[j] = *(const bf16x8*)&Xt[(j * 16 + row) * 264 + c0];
        #pragma unroll
        for (int t = 0; t < 3; ++t) {
            #pragma unroll
            for (int mi = 0; mi < 2; ++mi) {
                bf16x8 afrag = *(const bf16x8*)&wptr[t][(size_t)(ci_base + mi * 16 + row) * NC + c0];
                #pragma unroll
                for (int j = 0; j < 4; ++j)
                    acc[t][mi][j] = __builtin_amdgcn_mfma_f32_16x16x32_bf16(
                        afrag, bfrag[j], acc[t][mi][j], 0, 0, 0);
            }
        }
    }

    // Epilogue: +bias (fp32), write Qt/Kt (n,128) bf16 8B stores, V (128,n) bf16 scalar.
    size_t qkbase = ((size_t)s * NB + b) * NHW * NCI;
    size_t vbase  = ((size_t)s * NB + b) * NCI * NHW;
    #pragma unroll
    for (int mi = 0; mi < 2; ++mi) {
        int ci0 = ci_base + mi * 16 + quad * 4;
        f32x4 bq4 = *(const f32x4*)&bq[ci0];
        f32x4 bk4 = *(const f32x4*)&bk[ci0];
        f32x4 bv4 = *(const f32x4*)&bv[ci0];
        #pragma unroll
        for (int j = 0; j < 4; ++j) {
            int n = n0 + j * 16 + row;   // D col = lane&15
            bf16x4 pk;
            #pragma unroll
            for (int r = 0; r < 4; ++r) pk[r] = (bf16)(acc[0][mi][j][r] + bq4[r]);
            *(bf16x4*)&Qt[qkbase + (size_t)n * NCI + ci0] = pk;
            #pragma unroll
            for (int r = 0; r < 4; ++r) pk[r] = (bf16)(acc[1][mi][j][r] + bk4[r]);
            *(bf16x4*)&Kt[qkbase + (size_t)n * NCI + ci0] = pk;
            #pragma unroll
            for (int r = 0; r < 4; ++r)
                Vt[vbase + (size_t)(ci0 + r) * NHW + n] = (bf16)(acc[2][mi][j][r] + bv4[r]);
        }
    }
}

__global__ __launch_bounds__(256) void attn_kernel(
    const bf16* __restrict__ Qt, const bf16* __restrict__ Kt, const bf16* __restrict__ Vt,
    float* __restrict__ out)
{
    // Per-wave private P strip: 16 rows x 64 m, padded to 72 (144B stride, 16B aligned)
    __shared__ __align__(16) bf16 P[4][16 * 72];

    int gid = blockIdx.x;
    int ntile = gid % NTILES;
    int dir = (gid / NTILES) & 1;        // 0: Fu1 = sig(Q1^T K2) V2 ; 1: Fu2
    int b = gid / (2 * NTILES);
    int n0 = ntile * 64;

    int tid = threadIdx.x;
    int lane = tid & 63, w = tid >> 6;
    int row = lane & 15, quad = lane >> 4;

    int sq = dir, skv = dir ^ 1;
    const bf16* q = Qt + ((size_t)sq  * NB + b) * (NHW * NCI);
    const bf16* k = Kt + ((size_t)skv * NB + b) * (NHW * NCI);
    const bf16* v = Vt + ((size_t)skv * NB + b) * (NCI * NHW);
    float* outy = out + (size_t)dir * (NB * 384 * NHW) + ((size_t)b * 384 + 256) * NHW;

    int nw = n0 + w * 16;                // this wave's 16 Q rows
    bf16x8 qf[4];                        // Q A-frags, resident across m-loop
    #pragma unroll
    for (int ks = 0; ks < 4; ++ks)
        qf[ks] = *(const bf16x8*)&q[(size_t)(nw + row) * NCI + ks * 32 + quad * 8];

    f32x4 o[8];                          // O acc: 16 rows x 128 c
    #pragma unroll
    for (int ct = 0; ct < 8; ++ct) o[ct] = (f32x4){0.f, 0.f, 0.f, 0.f};

    bf16* Pw = P[w];

    for (int mt = 0; mt < NTILES; ++mt) {
        int m0 = mt * 64;
        // S = Q^T K for 16 n-rows x 64 m-cols
        f32x4 sacc[4];
        #pragma unroll
        for (int j = 0; j < 4; ++j) sacc[j] = (f32x4){0.f, 0.f, 0.f, 0.f};
        #pragma unroll
        for (int ks = 0; ks < 4; ++ks) {
            #pragma unroll
            for (int j = 0; j < 4; ++j) {
                bf16x8 kf = *(const bf16x8*)&k[(size_t)(m0 + j * 16 + row) * NCI + ks * 32 + quad * 8];
                sacc[j] = __builtin_amdgcn_mfma_f32_16x16x32_bf16(qf[ks], kf, sacc[j], 0, 0, 0);
            }
        }
        // sigmoid -> P (C/D layout -> LDS -> A-operand layout); P strip is wave-private,
        // same-wave DS ordering makes this safe without barriers.
        #pragma unroll
        for (int j = 0; j < 4; ++j) {
            #pragma unroll
            for (int r = 0; r < 4; ++r) {
                float xv = sacc[j][r];
                float e = __expf(-xv);
                float p = __builtin_amdgcn_rcpf(1.0f + e);
                Pw[(quad * 4 + r) * 72 + j * 16 + row] = (bf16)p;
            }
        }
        __syncthreads();
        // O += P * V^T  (A = P from LDS, B = V natural layout, contiguous in m)
        #pragma unroll
        for (int ks = 0; ks < 2; ++ks) {
            bf16x8 af = *(const bf16x8*)&Pw[row * 72 + ks * 32 + quad * 8];
            #pragma unroll
            for (int ct = 0; ct < 8; ++ct) {
                bf16x8 vf = *(const bf16x8*)&v[(size_t)(ct * 16 + row) * NHW + m0 + ks * 32 + quad * 8];
                o[ct] = __builtin_amdgcn_mfma_f32_16x16x32_bf16(af, vf, o[ct], 0, 0, 0);
            }
        }
    }

    // Write Fu (fp32): D col = c, rows = 4 consecutive n -> 16B stores
    int nbase = nw + quad * 4;
    #pragma unroll
    for (int ct = 0; ct < 8; ++ct) {
        int c = ct * 16 + row;
        *(f32x4*)&outy[(size_t)c * NHW + nbase] = o[ct];
    }
}

extern "C" void kernel_launch(void* const* d_in, const int* in_sizes, int n_in,
                              void* d_out, int out_size, void* d_ws, size_t ws_size,
                              hipStream_t stream) {
    const float* x1  = (const float*)d_in[0];
    const float* x2  = (const float*)d_in[1];
    const float* wv1 = (const float*)d_in[2];  const float* bv1 = (const float*)d_in[3];
    const float* wk1 = (const float*)d_in[4];  const float* bk1 = (const float*)d_in[5];
    const float* wq1 = (const float*)d_in[6];  const float* bq1 = (const float*)d_in[7];
    const float* wv2 = (const float*)d_in[8];  const float* bv2 = (const float*)d_in[9];
    const float* wk2 = (const float*)d_in[10]; const float* bk2 = (const float*)d_in[11];
    const float* wq2 = (const float*)d_in[12]; const float* bq2 = (const float*)d_in[13];
    float* out = (float*)d_out;

    // ws layout (bf16): Qt[2][B][2304][128] | Kt | Vt[2][B][128][2304] | wb[6][128*256]
    size_t per = (size_t)2 * NB * NHW * NCI;
    bf16* Qt = (bf16*)d_ws;
    bf16* Kt = Qt + per;
    bf16* Vt = Kt + per;
    bf16* wb = Vt + per;

    wconv_kernel<<<dim3(96), dim3(256), 0, stream>>>(wv1, wk1, wq1, wv2, wk2, wq2, wb);

    dim3 grid(NB * 2 * NTILES);   // 576
    dim3 block(256);
    qkv_kernel<<<grid, block, 0, stream>>>(x1, x2, wb, bv1, bk1, bq1, bv2, bk2, bq2,
                                           Qt, Kt, Vt, out);
    attn_kernel<<<grid, block, 0, stream>>>(Qt, Kt, Vt, out);
}